// Round 19
// baseline (262.944 us; speedup 1.0000x reference)
//
#include <hip/hip_runtime.h>
#include <math.h>

// Problem constants (from reference)
#define Bb 2
#define Ll 2048
#define Dd 512
#define Hh 8
#define DKq 64
#define NBUCK 16
#define KMAX 64
#define MAX_ITEMS 2304   // chunk-16 bound: 16 bh * (128 + 16) = 2304

// ---------------------------------------------------------------------------
// Direct global->LDS DMA (gfx950), 16B per lane.
// ---------------------------------------------------------------------------
__device__ __forceinline__ void gl_lds16(const float* g, float* l) {
  __builtin_amdgcn_global_load_lds(
      (const __attribute__((address_space(1))) void*)g,
      (__attribute__((address_space(3))) void*)l, 16, 0, 0);
}

// Counted vmcnt wait, NO barrier (single-wave blocks are self-paced).
// vmcnt retires IN ORDER: with only staging DMAs on the counter,
// vmcnt(N) == "tile t's N loads done, t+1's N may fly".
#define VM_WAIT(N)                                                \
  do {                                                            \
    asm volatile("s_waitcnt vmcnt(" #N ")" ::: "memory");         \
    __builtin_amdgcn_sched_barrier(0);                            \
  } while (0)

// ---------------------------------------------------------------------------
// Projection GEMM v8: X(4096x512) @ W(512x512) + b -> (b,h,l,dk) scatter.
// Round-19: BM=16 BN=64 BK=16, 4x4 microtile, grid (8,256,3) = 6144 blocks
// = 24 blocks/CU requested (15 resident, LDS 10KB) -- R18 analysis: the
// occupancy cap was the GRID (3072 blocks = 12/CU), not LDS/VGPR; the
// latency-bound self-paced wave wants more TLP (R13 lever, continued).
// A tile = 1 DMA load w/ k4 XOR (row>>3) swizzle (2-way banks = free);
// B = 4 loads; VM_WAIT(5) steady.  Per-output FMA chain ascending-k,
// one fma/k -> bit-identical q/k vs all prior rounds (LSH sign-critical).
// ---------------------------------------------------------------------------
__global__ __launch_bounds__(64) void proj_kernel(
    const float* __restrict__ Xq, const float* __restrict__ Xk, const float* __restrict__ Xv,
    const float* __restrict__ Wq, const float* __restrict__ Wk, const float* __restrict__ Wv,
    const float* __restrict__ bq, const float* __restrict__ bk, const float* __restrict__ bv,
    float* __restrict__ qb, float* __restrict__ kb, float* __restrict__ vb)
{
  const float *X, *W, *bias; float* dst;
  if (blockIdx.z == 0)      { X=Xq; W=Wq; bias=bq; dst=qb; }
  else if (blockIdx.z == 1) { X=Xk; W=Wk; bias=bk; dst=kb; }
  else                      { X=Xv; W=Wv; bias=bv; dst=vb; }
  __shared__ float As[2][16 * 16];    // 1 KB each
  __shared__ float Bs[2][16 * 64];    // 4 KB each
  const int lane = threadIdx.x;
  const int m0 = blockIdx.y * 16;
  const int n0 = blockIdx.x * 64;
  const int tx = lane & 15, ty = lane >> 4;     // 16 x 4 grid; 4x4 microtile

  // A DMA source, pre-swizzled: LDS slot s of row m holds X[m][(s^key(m))*4..],
  // key(m) = (m>>3)&3 (0/1 for m<16) -- read-side banks 2-way (free).
  const float* aSrc0;
  {
    int row  = lane >> 2;                       // 0..15
    int key  = (row >> 3) & 3;
    int sK4  = (lane & 3) ^ key;
    aSrc0 = X + (size_t)(m0 + row) * 512 + (sK4 << 2);
  }
  // B DMA source (linear): instr j covers k-rows 4j..4j+3 of the 16x64 tile.
  const float* bSrc[4];
  #pragma unroll
  for (int j = 0; j < 4; j++) {
    int krow = 4*j + (lane >> 4);               // 0..15
    bSrc[j] = W + (size_t)krow * 512 + n0 + ((lane & 15) << 2);
  }

  // Prologue: stage tile 0 into buf 0 (5 loads).
  gl_lds16(aSrc0, &As[0][0]);
  #pragma unroll
  for (int j = 0; j < 4; j++) gl_lds16(bSrc[j], &Bs[0][j*256]);

  float acc[4][4] = {};
  for (int t = 0; t < 32; t++) {
    const int cur = t & 1;
    if (t < 31) {                               // stage tile t+1 (5 loads)
      const int ks = (t + 1) * 16;
      const int nb = cur ^ 1;
      gl_lds16(aSrc0 + ks, &As[nb][0]);
      #pragma unroll
      for (int j = 0; j < 4; j++) gl_lds16(bSrc[j] + (size_t)ks*512, &Bs[nb][j*256]);
      VM_WAIT(5);                               // tile t landed; t+1 in flight
    } else {
      VM_WAIT(0);
    }

    const float* Ac = &As[cur][0];
    const float* Bc = &Bs[cur][0];
    #pragma unroll
    for (int kk4 = 0; kk4 < 4; kk4++) {
      float4 a[4];
      #pragma unroll
      for (int i = 0; i < 4; i++) {
        const int rr = ty*4 + i;
        a[i] = *(const float4*)&Ac[rr*16 + ((kk4 ^ ((rr >> 3) & 3)) << 2)];
      }
      #pragma unroll
      for (int s = 0; s < 4; s++) {
        const int kk = kk4*4 + s;
        float4 b0 = *(const float4*)&Bc[kk*64 + tx*4];
        #pragma unroll
        for (int i = 0; i < 4; i++) {
          const float as = (s==0) ? a[i].x : (s==1) ? a[i].y
                         : (s==2) ? a[i].z : a[i].w;
          acc[i][0] += as * b0.x;  acc[i][1] += as * b0.y;
          acc[i][2] += as * b0.z;  acc[i][3] += as * b0.w;
        }
      }
    }
    // 2-buffer safety (single wave): buf[cur^1] is only overwritten by the
    // NEXT iteration's stage, issued after these ds_reads in program order.
  }

  const int head = n0 >> 6;            // BN=64 == one head
  const int d0 = tx * 4;
  #pragma unroll
  for (int i = 0; i < 4; i++) {
    int m = m0 + ty*4 + i;
    int b = m >> 11, l = m & 2047;
    float* drow = &dst[(((size_t)b*Hh + head)*Ll + l)*DKq];
    #pragma unroll
    for (int j = 0; j < 4; j++) drow[d0 + j] = acc[i][j] + bias[n0 + tx*4 + j];
  }
}

// ---------------------------------------------------------------------------
// LSH hash (unchanged)
// ---------------------------------------------------------------------------
__global__ __launch_bounds__(256) void hash_kernel(
    const float* __restrict__ qb, const float* __restrict__ kb,
    const float* __restrict__ rv, int* __restrict__ qhash, int* __restrict__ khash)
{
  int gwave = (blockIdx.x * blockDim.x + threadIdx.x) >> 6;
  int lane = threadIdx.x & 63;
  const int NR = Bb * Hh * Ll;
  if (gwave >= 2 * NR) return;
  int isK = gwave >= NR;
  int row = isK ? gwave - NR : gwave;
  int h = (row >> 11) & 7;
  const float* src = isK ? kb : qb;
  float x = src[(size_t)row * DKq + lane];
  float r = rv[h * DKq + lane];
  float v = (x > 0.0f) ? r : 0.0f;
  #pragma unroll
  for (int off = 32; off; off >>= 1) v += __shfl_xor(v, off);
  if (lane == 0) {
    float fb = floorf(v * 0.125f);
    int ib = (int)fb;
    int bucket = ib & 15;
    (isK ? khash : qhash)[row] = bucket;
  }
}

// ---------------------------------------------------------------------------
// Fused bucketing (unchanged from rounds 17/18 -- verified): qlist
// counting-sort + kcand ballot scans + item emission via atomicAdd.
// Item ORDER nondeterministic; item set and per-query outputs deterministic.
// ---------------------------------------------------------------------------
__global__ __launch_bounds__(256) void bucket_kernel(
    const int* __restrict__ qhash, const int* __restrict__ khash,
    int* __restrict__ qlist, int* __restrict__ kcand,
    int4* __restrict__ items, int* __restrict__ nitems)
{
  const int bh = blockIdx.x;
  const int tid = threadIdx.x;
  __shared__ int cnt[NBUCK], cur[NBUCK], off[NBUCK + 1], kc[NBUCK];
  if (tid < NBUCK) cnt[tid] = 0;
  __syncthreads();
  const int* qh = &qhash[bh * Ll];
  for (int l = tid; l < Ll; l += 256) atomicAdd(&cnt[qh[l]], 1);
  __syncthreads();
  if (tid == 0) {
    int s = 0;
    for (int i = 0; i < NBUCK; i++) { off[i] = s; cur[i] = s; s += cnt[i]; }
    off[NBUCK] = s;
  }
  __syncthreads();
  for (int l = tid; l < Ll; l += 256) {
    int p = atomicAdd(&cur[qh[l]], 1);
    qlist[bh * Ll + p] = l;
  }
  const int lane = tid & 63, w = tid >> 6;
  const int* kh = &khash[bh * Ll];
  for (int bi = 0; bi < 4; bi++) {
    int bucket = w * 4 + bi;
    int* cl = &kcand[((size_t)bh * NBUCK + bucket) * KMAX];
    int total = 0;
    for (int c0 = 0; c0 < Ll && total < KMAX; c0 += 64) {
      int hv = kh[c0 + lane];
      unsigned long long mm = __ballot(hv == bucket);
      int pre = __popcll(mm & ((1ULL << lane) - 1ULL));
      if (hv == bucket && total + pre < KMAX) cl[total + pre] = c0 + lane;
      total += __popcll(mm);
    }
    if (lane == 0) kc[bucket] = total < KMAX ? total : KMAX;
  }
  __syncthreads();
  if (tid < NBUCK) {
    const int bucket = tid;
    int nq = off[bucket + 1] - off[bucket];
    int cb = kc[bucket];
    int n = (cb > 0) ? ((nq + 15) >> 4) : 0;
    if (n > 0) {
      int base = atomicAdd(nitems, n);
      for (int i = 0; i < n; i++) {
        int q0 = 16 * i;
        int qn = nq - q0; if (qn > 16) qn = 16;
        items[base + i] = make_int4(bh * NBUCK + bucket, off[bucket] + q0, qn, cb);
      }
    }
  }
}

// ---------------------------------------------------------------------------
// LDS fence for same-wave cross-lane LDS dependences (rule #18).
// ---------------------------------------------------------------------------
__device__ __forceinline__ void lds_fence() {
  asm volatile("s_waitcnt lgkmcnt(0)" ::: "memory");
  __builtin_amdgcn_sched_barrier(0);
}

// ---------------------------------------------------------------------------
// Attention (unchanged from round 16): one WAVE per item (<=16 q), paired
// query processing, K in regs (lane=c), V^T in regs (lane=d).
// ---------------------------------------------------------------------------
__global__ __launch_bounds__(256, 2) void attn_kernel(
    const float* __restrict__ qb, const float* __restrict__ kb, const float* __restrict__ vb,
    const int* __restrict__ qlist, const int* __restrict__ kcand,
    const int4* __restrict__ items, const int* __restrict__ nitems,
    float* __restrict__ ctx)
{
  __shared__ float qs_all[4][16 * 64];
  __shared__ float sa_all[4][128];
  const int wid = threadIdx.x >> 6, lane = threadIdx.x & 63;
  const int idx = blockIdx.x * 4 + wid;
  if (idx >= nitems[0]) return;          // wave-uniform exit
  const int4 it = items[idx];
  const int code = it.x, qstart = it.y, qn = it.z, cnt = it.w;
  const int bh = code >> 4;
  float* qs = qs_all[wid];
  float* sa = sa_all[wid];

  const float* qbh = qb + (size_t)bh * Ll * DKq;
  const float* kbh = kb + (size_t)bh * Ll * DKq;
  const float* vbh = vb + (size_t)bh * Ll * DKq;

  int qidx_v = (lane < qn)  ? qlist[bh * Ll + qstart + lane] : 0;
  int cidx_v = (lane < cnt) ? kcand[(size_t)code * KMAX + lane] : 0;

  float4 kr[16];
  {
    const float4* krow = (const float4*)kbh + (size_t)cidx_v * 16;
    #pragma unroll
    for (int i = 0; i < 16; i++) kr[i] = krow[i];
  }
  float vt[64];
  #pragma unroll
  for (int c = 0; c < 64; c++) {
    int rowc = __shfl(cidx_v, c);
    vt[c] = vbh[(size_t)rowc * DKq + lane];
  }
  #pragma unroll
  for (int i = 0; i < 4; i++) {
    int f = lane + 64 * i;
    int r = f >> 4, c4 = f & 15;
    int qrow = __shfl(qidx_v, r);
    float4 qv = *((const float4*)qbh + (size_t)qrow * 16 + c4);
    *(float4*)&qs[r * 64 + c4 * 4] = qv;
  }
  lds_fence();

  const int b = bh >> 3, h = bh & 7;
  const float4* qs4 = (const float4*)qs;
  const float4* sa4 = (const float4*)sa;

  for (int jj = 0; jj < qn; jj += 2) {
    const int j0  = jj;
    const int j1v = jj + 1;
    const int j1r = (j1v < qn) ? j1v : j0;
    float p00=0.f,p01=0.f,p02=0.f,p03=0.f;
    float p10=0.f,p11=0.f,p12=0.f,p13=0.f;
    #pragma unroll
    for (int i = 0; i < 16; i += 4) {
      float4 qA0 = qs4[j0*16 + i + 0];
      float4 qA1 = qs4[j0*16 + i + 1];
      float4 qA2 = qs4[j0*16 + i + 2];
      float4 qA3 = qs4[j0*16 + i + 3];
      float4 qB0 = qs4[j1r*16 + i + 0];
      float4 qB1 = qs4[j1r*16 + i + 1];
      float4 qB2 = qs4[j1r*16 + i + 2];
      float4 qB3 = qs4[j1r*16 + i + 3];
      p00 += qA0.x*kr[i+0].x + qA0.y*kr[i+0].y + qA0.z*kr[i+0].z + qA0.w*kr[i+0].w;
      p01 += qA1.x*kr[i+1].x + qA1.y*kr[i+1].y + qA1.z*kr[i+1].z + qA1.w*kr[i+1].w;
      p02 += qA2.x*kr[i+2].x + qA2.y*kr[i+2].y + qA2.z*kr[i+2].z + qA2.w*kr[i+2].w;
      p03 += qA3.x*kr[i+3].x + qA3.y*kr[i+3].y + qA3.z*kr[i+3].z + qA3.w*kr[i+3].w;
      p10 += qB0.x*kr[i+0].x + qB0.y*kr[i+0].y + qB0.z*kr[i+0].z + qB0.w*kr[i+0].w;
      p11 += qB1.x*kr[i+1].x + qB1.y*kr[i+1].y + qB1.z*kr[i+1].z + qB1.w*kr[i+1].w;
      p12 += qB2.x*kr[i+2].x + qB2.y*kr[i+2].y + qB2.z*kr[i+2].z + qB2.w*kr[i+2].w;
      p13 += qB3.x*kr[i+3].x + qB3.y*kr[i+3].y + qB3.z*kr[i+3].z + qB3.w*kr[i+3].w;
    }
    float sA = ((p00 + p01) + (p02 + p03)) * 0.125f;
    float sB = ((p10 + p11) + (p12 + p13)) * 0.125f;
    sA = (lane < cnt) ? sA : -INFINITY;
    sB = (lane < cnt) ? sB : -INFINITY;
    float mA = sA, mB = sB;
    #pragma unroll
    for (int off = 32; off; off >>= 1) {
      mA = fmaxf(mA, __shfl_xor(mA, off));
      mB = fmaxf(mB, __shfl_xor(mB, off));
    }
    float eA = __expf(sA - mA);
    float eB = __expf(sB - mB);
    float sumA = eA, sumB = eB;
    #pragma unroll
    for (int off = 32; off; off >>= 1) {
      sumA += __shfl_xor(sumA, off);
      sumB += __shfl_xor(sumB, off);
    }
    lds_fence();
    sa[lane]      = eA;
    sa[64 + lane] = eB;
    lds_fence();
    float c00=0.f,c01=0.f,c02=0.f,c03=0.f;
    float c10=0.f,c11=0.f,c12=0.f,c13=0.f;
    #pragma unroll
    for (int i = 0; i < 16; i++) {
      float4 aA = sa4[i];
      float4 aB = sa4[16 + i];
      c00 += aA.x * vt[4*i + 0];
      c01 += aA.y * vt[4*i + 1];
      c02 += aA.z * vt[4*i + 2];
      c03 += aA.w * vt[4*i + 3];
      c10 += aB.x * vt[4*i + 0];
      c11 += aB.y * vt[4*i + 1];
      c12 += aB.z * vt[4*i + 2];
      c13 += aB.w * vt[4*i + 3];
    }
    {
      float ctxd = ((c00 + c01) + (c02 + c03)) / sumA;
      int qrow = __shfl(qidx_v, j0);
      ctx[((size_t)(b * Ll + qrow)) * 512 + h * 64 + lane] = ctxd;
    }
    if (j1v < qn) {
      float ctxd = ((c10 + c11) + (c12 + c13)) / sumB;
      int qrow = __shfl(qidx_v, j1v);
      ctx[((size_t)(b * Ll + qrow)) * 512 + h * 64 + lane] = ctxd;
    }
  }
}

// ---------------------------------------------------------------------------
// T[h,dk,n] = sum_r U[h,dk,r] * V[h,r,n]  (unchanged)
// ---------------------------------------------------------------------------
__global__ __launch_bounds__(256) void uv_kernel(
    const float* __restrict__ U, const float* __restrict__ V, float* __restrict__ T)
{
  int idx = blockIdx.x * 256 + threadIdx.x;
  int n = idx & 511, dk = (idx >> 9) & 63, h = idx >> 15;
  float acc = 0.f;
  #pragma unroll
  for (int r = 0; r < 32; r++)
    acc += U[((size_t)h * 64 + dk) * 32 + r] * V[((size_t)h * 32 + r) * 512 + n];
  T[idx] = acc;
}

// ---------------------------------------------------------------------------
// Mf[h*64+dk, n] = sum_c T[h,dk,c] * Wo[h*512+c, n].  (unchanged R15)
// ---------------------------------------------------------------------------
__global__ __launch_bounds__(64) void m_kernel(
    const float* __restrict__ T, const float* __restrict__ Wo, float* __restrict__ Mf)
{
  __shared__ float As[2][32 * 16];
  __shared__ float Bs[2][16 * 64];
  const int lane = threadIdx.x;
  const int h  = blockIdx.z;
  const int m0 = blockIdx.y * 32;
  const int n0 = blockIdx.x * 64;
  const int tx = lane & 15, ty = lane >> 4;

  const float* Tb = T + (size_t)h * 64 * 512;
  const float* Wb = Wo + (size_t)h * 512 * 512;

  const float* aSrc[2];
  #pragma unroll
  for (int j = 0; j < 2; j++) {
    int row  = 16*j + (lane >> 2);
    int key  = (row >> 3) & 3;
    int sK4  = (lane & 3) ^ key;
    aSrc[j] = Tb + (size_t)(m0 + row) * 512 + (sK4 << 2);
  }
  const float* bSrc[4];
  #pragma unroll
  for (int j = 0; j < 4; j++) {
    int krow = 4*j + (lane >> 4);
    bSrc[j] = Wb + (size_t)krow * 512 + n0 + ((lane & 15) << 2);
  }

  #pragma unroll
  for (int j = 0; j < 2; j++) gl_lds16(aSrc[j], &As[0][j*256]);
  #pragma unroll
  for (int j = 0; j < 4; j++) gl_lds16(bSrc[j], &Bs[0][j*256]);

  float acc[8][4] = {};
  for (int t = 0; t < 32; t++) {
    const int cur = t & 1;
    if (t < 31) {
      const int ks = (t + 1) * 16;
      const int nb = cur ^ 1;
      #pragma unroll
      for (int j = 0; j < 2; j++) gl_lds16(aSrc[j] + ks,              &As[nb][j*256]);
      #pragma unroll
      for (int j = 0; j < 4; j++) gl_lds16(bSrc[j] + (size_t)ks*512,  &Bs[nb][j*256]);
      VM_WAIT(6);
    } else {
      VM_WAIT(0);
    }

    const float* Ac = &As[cur][0];
    const float* Bc = &Bs[cur][0];
    #pragma unroll
    for (int kk4 = 0; kk4 < 4; kk4++) {
      float4 a[8];
      #pragma unroll
      for (int i = 0; i < 8; i++)
        a[i] = *(const float4*)&Ac[(ty*8 + i)*16 + ((kk4 ^ ty) << 2)];
      #pragma unroll
      for (int s = 0; s < 4; s++) {
        const int kk = kk4*4 + s;
        float4 b0 = *(const float4*)&Bc[kk*64 + tx*4];
        #pragma unroll
        for (int i = 0; i < 8; i++) {
          const float as = (s==0) ? a[i].x : (s==1) ? a[i].y
                         : (s==2) ? a[i].z : a[i].w;
          acc[i][0] += as * b0.x;  acc[i][1] += as * b0.y;
          acc[i][2] += as * b0.z;  acc[i][3] += as * b0.w;
        }
      }
    }
  }

  #pragma unroll
  for (int i = 0; i < 8; i++) {
    int row = h*64 + m0 + ty*8 + i;
    #pragma unroll
    for (int j = 0; j < 4; j++)
      Mf[(size_t)row * 512 + n0 + tx*4 + j] = acc[i][j];
  }
}

// ---------------------------------------------------------------------------
// OUT(4096x512) = CTX @ Mf + bo.  (unchanged R15)
// ---------------------------------------------------------------------------
__global__ __launch_bounds__(64) void out_gemm(
    const float* __restrict__ A, const float* __restrict__ Bm,
    const float* __restrict__ bias, float* __restrict__ C)
{
  __shared__ float As[2][32 * 16];
  __shared__ float Bs[2][16 * 64];
  const int lane = threadIdx.x;
  const int m0 = blockIdx.y * 32;
  const int n0 = blockIdx.x * 64;
  const int tx = lane & 15, ty = lane >> 4;

  const float* aSrc[2];
  #pragma unroll
  for (int j = 0; j < 2; j++) {
    int row  = 16*j + (lane >> 2);
    int key  = (row >> 3) & 3;
    int sK4  = (lane & 3) ^ key;
    aSrc[j] = A + (size_t)(m0 + row) * 512 + (sK4 << 2);
  }
  const float* bSrc[4];
  #pragma unroll
  for (int j = 0; j < 4; j++) {
    int krow = 4*j + (lane >> 4);
    bSrc[j] = Bm + (size_t)krow * 512 + n0 + ((lane & 15) << 2);
  }

  #pragma unroll
  for (int j = 0; j < 2; j++) gl_lds16(aSrc[j], &As[0][j*256]);
  #pragma unroll
  for (int j = 0; j < 4; j++) gl_lds16(bSrc[j], &Bs[0][j*256]);

  float acc[8][4] = {};
  for (int t = 0; t < 32; t++) {
    const int cur = t & 1;
    if (t < 31) {
      const int ks = (t + 1) * 16;
      const int nb = cur ^ 1;
      #pragma unroll
      for (int j = 0; j < 2; j++) gl_lds16(aSrc[j] + ks,              &As[nb][j*256]);
      #pragma unroll
      for (int j = 0; j < 4; j++) gl_lds16(bSrc[j] + (size_t)ks*512,  &Bs[nb][j*256]);
      VM_WAIT(6);
    } else {
      VM_WAIT(0);
    }

    const float* Ac = &As[cur][0];
    const float* Bc = &Bs[cur][0];
    #pragma unroll
    for (int kk4 = 0; kk4 < 4; kk4++) {
      float4 a[8];
      #pragma unroll
      for (int i = 0; i < 8; i++)
        a[i] = *(const float4*)&Ac[(ty*8 + i)*16 + ((kk4 ^ ty) << 2)];
      #pragma unroll
      for (int s = 0; s < 4; s++) {
        const int kk = kk4*4 + s;
        float4 b0 = *(const float4*)&Bc[kk*64 + tx*4];
        #pragma unroll
        for (int i = 0; i < 8; i++) {
          const float as = (s==0) ? a[i].x : (s==1) ? a[i].y
                         : (s==2) ? a[i].z : a[i].w;
          acc[i][0] += as * b0.x;  acc[i][1] += as * b0.y;
          acc[i][2] += as * b0.z;  acc[i][3] += as * b0.w;
        }
      }
    }
  }

  #pragma unroll
  for (int i = 0; i < 8; i++) {
    int m = m0 + ty*8 + i;
    #pragma unroll
    for (int j = 0; j < 4; j++) {
      int n = n0 + tx*4 + j;
      C[(size_t)m * 512 + n] = acc[i][j] + bias[n];
    }
  }
}

// ---------------------------------------------------------------------------
extern "C" void kernel_launch(void* const* d_in, const int* in_sizes, int n_in,
                              void* d_out, int out_size, void* d_ws, size_t ws_size,
                              hipStream_t stream)
{
  const float* query = (const float*)d_in[0];
  const float* key   = (const float*)d_in[1];
  const float* value = (const float*)d_in[2];
  const float* Wq = (const float*)d_in[3];
  const float* bq = (const float*)d_in[4];
  const float* Wk = (const float*)d_in[5];
  const float* bk = (const float*)d_in[6];
  const float* Wv = (const float*)d_in[7];
  const float* bv = (const float*)d_in[8];
  const float* U  = (const float*)d_in[9];
  const float* V  = (const float*)d_in[10];
  const float* rv = (const float*)d_in[11];
  const float* Wo = (const float*)d_in[12];
  const float* bo = (const float*)d_in[13];
  float* out = (float*)d_out;

  float* ws = (float*)d_ws;
  const size_t NQKV = (size_t)Bb * Hh * Ll * DKq;
  float* qb   = ws;
  float* kb   = qb + NQKV;
  float* vb   = kb + NQKV;
  float* ctx  = vb + NQKV;
  float* T    = ctx + NQKV;
  float* Mf   = T + (size_t)Hh * DKq * 512;
  int* qhash  = (int*)(Mf + 512 * 512);
  int* khash  = qhash + Bb * Hh * Ll;
  int* kcand  = khash + Bb * Hh * Ll;
  int* kcount = kcand + Bb * Hh * NBUCK * KMAX;   // unused (layout keep)
  int* qoff   = kcount + Bb * Hh * NBUCK;         // unused (layout keep)
  int* qlist  = qoff + Bb * Hh * (NBUCK + 1);
  int4* items = (int4*)(qlist + Bb * Hh * Ll);    // 16B-aligned offset
  int* nitems = (int*)(items + MAX_ITEMS);

  proj_kernel<<<dim3(8, 256, 3), 64, 0, stream>>>(query, key, value,
                                                  Wq, Wk, Wv, bq, bk, bv,
                                                  qb, kb, vb);
  hash_kernel<<<(2 * Bb * Hh * Ll * 64) / 256, 256, 0, stream>>>(qb, kb, rv, qhash, khash);
  hipMemsetAsync(nitems, 0, sizeof(int), stream);
  bucket_kernel<<<Bb * Hh, 256, 0, stream>>>(qhash, khash, qlist, kcand, items, nitems);
  attn_kernel<<<MAX_ITEMS / 4, 256, 0, stream>>>(qb, kb, vb, qlist, kcand,
                                                 items, nitems, ctx);
  uv_kernel<<<(Hh * DKq * 512) / 256, 256, 0, stream>>>(U, V, T);
  m_kernel<<<dim3(8, 2, 8), 64, 0, stream>>>(T, Wo, Mf);
  out_gemm<<<dim3(8, 128), 64, 0, stream>>>(ctx, Mf, bo, out);
}

// Round 20
// 262.680 us; speedup vs baseline: 1.0010x; 1.0010x over previous
//
#include <hip/hip_runtime.h>
#include <math.h>

// Problem constants (from reference)
#define Bb 2
#define Ll 2048
#define Dd 512
#define Hh 8
#define DKq 64
#define NBUCK 16
#define KMAX 64
#define MAX_ITEMS 2304   // chunk-16 bound: 16 bh * (128 + 16) = 2304

// ---------------------------------------------------------------------------
// Direct global->LDS DMA (gfx950), 16B per lane.
// ---------------------------------------------------------------------------
__device__ __forceinline__ void gl_lds16(const float* g, float* l) {
  __builtin_amdgcn_global_load_lds(
      (const __attribute__((address_space(1))) void*)g,
      (__attribute__((address_space(3))) void*)l, 16, 0, 0);
}

// Counted vmcnt wait, NO barrier (single-wave blocks are self-paced).
// vmcnt retires IN ORDER: with only staging DMAs on the counter,
// vmcnt(N) == "tile t's N loads done, t+1's N may fly".
#define VM_WAIT(N)                                                \
  do {                                                            \
    asm volatile("s_waitcnt vmcnt(" #N ")" ::: "memory");         \
    __builtin_amdgcn_sched_barrier(0);                            \
  } while (0)

// ---------------------------------------------------------------------------
// Projection GEMM v8b: X(4096x512) @ W(512x512) + b -> (b,h,l,dk) scatter.
// BM=16 BN=64 BK=16, 4x4 microtile, grid (8,256,3) = 6144 blocks.
// Round-20 FIX of round-19's swizzle-key bug: key was (row>>3)&3 which only
// spans {0,1} for 16 rows -> same-key row pairs (i,i+4) hit the SAME banks
// at different addrs = 2-way conflict on every A-read (12.58M measured).
// key = (row>>2)&3 gives the read's 4 row-groups the full quad permutation
// {kk4^0..kk4^3} -> 16 distinct banks, conflict-free.  Same values, same
// ascending-k FMA chain -> bit-identical q/k (LSH sign-critical).
// ---------------------------------------------------------------------------
__global__ __launch_bounds__(64) void proj_kernel(
    const float* __restrict__ Xq, const float* __restrict__ Xk, const float* __restrict__ Xv,
    const float* __restrict__ Wq, const float* __restrict__ Wk, const float* __restrict__ Wv,
    const float* __restrict__ bq, const float* __restrict__ bk, const float* __restrict__ bv,
    float* __restrict__ qb, float* __restrict__ kb, float* __restrict__ vb)
{
  const float *X, *W, *bias; float* dst;
  if (blockIdx.z == 0)      { X=Xq; W=Wq; bias=bq; dst=qb; }
  else if (blockIdx.z == 1) { X=Xk; W=Wk; bias=bk; dst=kb; }
  else                      { X=Xv; W=Wv; bias=bv; dst=vb; }
  __shared__ float As[2][16 * 16];    // 1 KB each
  __shared__ float Bs[2][16 * 64];    // 4 KB each
  const int lane = threadIdx.x;
  const int m0 = blockIdx.y * 16;
  const int n0 = blockIdx.x * 64;
  const int tx = lane & 15, ty = lane >> 4;     // 16 x 4 grid; 4x4 microtile

  // A DMA source, pre-swizzled: LDS slot s of row m holds X[m][(s^key(m))*4..],
  // key(m) = (m>>2)&3 -- 4 distinct keys across the read's row groups.
  const float* aSrc0;
  {
    int row  = lane >> 2;                       // 0..15
    int key  = (row >> 2) & 3;                  // R20 fix (was >>3)
    int sK4  = (lane & 3) ^ key;
    aSrc0 = X + (size_t)(m0 + row) * 512 + (sK4 << 2);
  }
  // B DMA source (linear): instr j covers k-rows 4j..4j+3 of the 16x64 tile.
  const float* bSrc[4];
  #pragma unroll
  for (int j = 0; j < 4; j++) {
    int krow = 4*j + (lane >> 4);               // 0..15
    bSrc[j] = W + (size_t)krow * 512 + n0 + ((lane & 15) << 2);
  }

  // Prologue: stage tile 0 into buf 0 (5 loads).
  gl_lds16(aSrc0, &As[0][0]);
  #pragma unroll
  for (int j = 0; j < 4; j++) gl_lds16(bSrc[j], &Bs[0][j*256]);

  float acc[4][4] = {};
  for (int t = 0; t < 32; t++) {
    const int cur = t & 1;
    if (t < 31) {                               // stage tile t+1 (5 loads)
      const int ks = (t + 1) * 16;
      const int nb = cur ^ 1;
      gl_lds16(aSrc0 + ks, &As[nb][0]);
      #pragma unroll
      for (int j = 0; j < 4; j++) gl_lds16(bSrc[j] + (size_t)ks*512, &Bs[nb][j*256]);
      VM_WAIT(5);                               // tile t landed; t+1 in flight
    } else {
      VM_WAIT(0);
    }

    const float* Ac = &As[cur][0];
    const float* Bc = &Bs[cur][0];
    #pragma unroll
    for (int kk4 = 0; kk4 < 4; kk4++) {
      float4 a[4];
      #pragma unroll
      for (int i = 0; i < 4; i++) {
        const int rr = ty*4 + i;
        a[i] = *(const float4*)&Ac[rr*16 + ((kk4 ^ ((rr >> 2) & 3)) << 2)];  // R20 fix
      }
      #pragma unroll
      for (int s = 0; s < 4; s++) {
        const int kk = kk4*4 + s;
        float4 b0 = *(const float4*)&Bc[kk*64 + tx*4];
        #pragma unroll
        for (int i = 0; i < 4; i++) {
          const float as = (s==0) ? a[i].x : (s==1) ? a[i].y
                         : (s==2) ? a[i].z : a[i].w;
          acc[i][0] += as * b0.x;  acc[i][1] += as * b0.y;
          acc[i][2] += as * b0.z;  acc[i][3] += as * b0.w;
        }
      }
    }
    // 2-buffer safety (single wave): buf[cur^1] is only overwritten by the
    // NEXT iteration's stage, issued after these ds_reads in program order.
  }

  const int head = n0 >> 6;            // BN=64 == one head
  const int d0 = tx * 4;
  #pragma unroll
  for (int i = 0; i < 4; i++) {
    int m = m0 + ty*4 + i;
    int b = m >> 11, l = m & 2047;
    float* drow = &dst[(((size_t)b*Hh + head)*Ll + l)*DKq];
    #pragma unroll
    for (int j = 0; j < 4; j++) drow[d0 + j] = acc[i][j] + bias[n0 + tx*4 + j];
  }
}

// ---------------------------------------------------------------------------
// LSH hash (unchanged)
// ---------------------------------------------------------------------------
__global__ __launch_bounds__(256) void hash_kernel(
    const float* __restrict__ qb, const float* __restrict__ kb,
    const float* __restrict__ rv, int* __restrict__ qhash, int* __restrict__ khash)
{
  int gwave = (blockIdx.x * blockDim.x + threadIdx.x) >> 6;
  int lane = threadIdx.x & 63;
  const int NR = Bb * Hh * Ll;
  if (gwave >= 2 * NR) return;
  int isK = gwave >= NR;
  int row = isK ? gwave - NR : gwave;
  int h = (row >> 11) & 7;
  const float* src = isK ? kb : qb;
  float x = src[(size_t)row * DKq + lane];
  float r = rv[h * DKq + lane];
  float v = (x > 0.0f) ? r : 0.0f;
  #pragma unroll
  for (int off = 32; off; off >>= 1) v += __shfl_xor(v, off);
  if (lane == 0) {
    float fb = floorf(v * 0.125f);
    int ib = (int)fb;
    int bucket = ib & 15;
    (isK ? khash : qhash)[row] = bucket;
  }
}

// ---------------------------------------------------------------------------
// Fused bucketing (unchanged from rounds 17/18 -- verified): qlist
// counting-sort + kcand ballot scans + item emission via atomicAdd.
// Item ORDER nondeterministic; item set and per-query outputs deterministic.
// ---------------------------------------------------------------------------
__global__ __launch_bounds__(256) void bucket_kernel(
    const int* __restrict__ qhash, const int* __restrict__ khash,
    int* __restrict__ qlist, int* __restrict__ kcand,
    int4* __restrict__ items, int* __restrict__ nitems)
{
  const int bh = blockIdx.x;
  const int tid = threadIdx.x;
  __shared__ int cnt[NBUCK], cur[NBUCK], off[NBUCK + 1], kc[NBUCK];
  if (tid < NBUCK) cnt[tid] = 0;
  __syncthreads();
  const int* qh = &qhash[bh * Ll];
  for (int l = tid; l < Ll; l += 256) atomicAdd(&cnt[qh[l]], 1);
  __syncthreads();
  if (tid == 0) {
    int s = 0;
    for (int i = 0; i < NBUCK; i++) { off[i] = s; cur[i] = s; s += cnt[i]; }
    off[NBUCK] = s;
  }
  __syncthreads();
  for (int l = tid; l < Ll; l += 256) {
    int p = atomicAdd(&cur[qh[l]], 1);
    qlist[bh * Ll + p] = l;
  }
  const int lane = tid & 63, w = tid >> 6;
  const int* kh = &khash[bh * Ll];
  for (int bi = 0; bi < 4; bi++) {
    int bucket = w * 4 + bi;
    int* cl = &kcand[((size_t)bh * NBUCK + bucket) * KMAX];
    int total = 0;
    for (int c0 = 0; c0 < Ll && total < KMAX; c0 += 64) {
      int hv = kh[c0 + lane];
      unsigned long long mm = __ballot(hv == bucket);
      int pre = __popcll(mm & ((1ULL << lane) - 1ULL));
      if (hv == bucket && total + pre < KMAX) cl[total + pre] = c0 + lane;
      total += __popcll(mm);
    }
    if (lane == 0) kc[bucket] = total < KMAX ? total : KMAX;
  }
  __syncthreads();
  if (tid < NBUCK) {
    const int bucket = tid;
    int nq = off[bucket + 1] - off[bucket];
    int cb = kc[bucket];
    int n = (cb > 0) ? ((nq + 15) >> 4) : 0;
    if (n > 0) {
      int base = atomicAdd(nitems, n);
      for (int i = 0; i < n; i++) {
        int q0 = 16 * i;
        int qn = nq - q0; if (qn > 16) qn = 16;
        items[base + i] = make_int4(bh * NBUCK + bucket, off[bucket] + q0, qn, cb);
      }
    }
  }
}

// ---------------------------------------------------------------------------
// LDS fence for same-wave cross-lane LDS dependences (rule #18).
// ---------------------------------------------------------------------------
__device__ __forceinline__ void lds_fence() {
  asm volatile("s_waitcnt lgkmcnt(0)" ::: "memory");
  __builtin_amdgcn_sched_barrier(0);
}

// ---------------------------------------------------------------------------
// Attention (unchanged from round 16): one WAVE per item (<=16 q), paired
// query processing, K in regs (lane=c), V^T in regs (lane=d).
// ---------------------------------------------------------------------------
__global__ __launch_bounds__(256, 2) void attn_kernel(
    const float* __restrict__ qb, const float* __restrict__ kb, const float* __restrict__ vb,
    const int* __restrict__ qlist, const int* __restrict__ kcand,
    const int4* __restrict__ items, const int* __restrict__ nitems,
    float* __restrict__ ctx)
{
  __shared__ float qs_all[4][16 * 64];
  __shared__ float sa_all[4][128];
  const int wid = threadIdx.x >> 6, lane = threadIdx.x & 63;
  const int idx = blockIdx.x * 4 + wid;
  if (idx >= nitems[0]) return;          // wave-uniform exit
  const int4 it = items[idx];
  const int code = it.x, qstart = it.y, qn = it.z, cnt = it.w;
  const int bh = code >> 4;
  float* qs = qs_all[wid];
  float* sa = sa_all[wid];

  const float* qbh = qb + (size_t)bh * Ll * DKq;
  const float* kbh = kb + (size_t)bh * Ll * DKq;
  const float* vbh = vb + (size_t)bh * Ll * DKq;

  int qidx_v = (lane < qn)  ? qlist[bh * Ll + qstart + lane] : 0;
  int cidx_v = (lane < cnt) ? kcand[(size_t)code * KMAX + lane] : 0;

  float4 kr[16];
  {
    const float4* krow = (const float4*)kbh + (size_t)cidx_v * 16;
    #pragma unroll
    for (int i = 0; i < 16; i++) kr[i] = krow[i];
  }
  float vt[64];
  #pragma unroll
  for (int c = 0; c < 64; c++) {
    int rowc = __shfl(cidx_v, c);
    vt[c] = vbh[(size_t)rowc * DKq + lane];
  }
  #pragma unroll
  for (int i = 0; i < 4; i++) {
    int f = lane + 64 * i;
    int r = f >> 4, c4 = f & 15;
    int qrow = __shfl(qidx_v, r);
    float4 qv = *((const float4*)qbh + (size_t)qrow * 16 + c4);
    *(float4*)&qs[r * 64 + c4 * 4] = qv;
  }
  lds_fence();

  const int b = bh >> 3, h = bh & 7;
  const float4* qs4 = (const float4*)qs;
  const float4* sa4 = (const float4*)sa;

  for (int jj = 0; jj < qn; jj += 2) {
    const int j0  = jj;
    const int j1v = jj + 1;
    const int j1r = (j1v < qn) ? j1v : j0;
    float p00=0.f,p01=0.f,p02=0.f,p03=0.f;
    float p10=0.f,p11=0.f,p12=0.f,p13=0.f;
    #pragma unroll
    for (int i = 0; i < 16; i += 4) {
      float4 qA0 = qs4[j0*16 + i + 0];
      float4 qA1 = qs4[j0*16 + i + 1];
      float4 qA2 = qs4[j0*16 + i + 2];
      float4 qA3 = qs4[j0*16 + i + 3];
      float4 qB0 = qs4[j1r*16 + i + 0];
      float4 qB1 = qs4[j1r*16 + i + 1];
      float4 qB2 = qs4[j1r*16 + i + 2];
      float4 qB3 = qs4[j1r*16 + i + 3];
      p00 += qA0.x*kr[i+0].x + qA0.y*kr[i+0].y + qA0.z*kr[i+0].z + qA0.w*kr[i+0].w;
      p01 += qA1.x*kr[i+1].x + qA1.y*kr[i+1].y + qA1.z*kr[i+1].z + qA1.w*kr[i+1].w;
      p02 += qA2.x*kr[i+2].x + qA2.y*kr[i+2].y + qA2.z*kr[i+2].z + qA2.w*kr[i+2].w;
      p03 += qA3.x*kr[i+3].x + qA3.y*kr[i+3].y + qA3.z*kr[i+3].z + qA3.w*kr[i+3].w;
      p10 += qB0.x*kr[i+0].x + qB0.y*kr[i+0].y + qB0.z*kr[i+0].z + qB0.w*kr[i+0].w;
      p11 += qB1.x*kr[i+1].x + qB1.y*kr[i+1].y + qB1.z*kr[i+1].z + qB1.w*kr[i+1].w;
      p12 += qB2.x*kr[i+2].x + qB2.y*kr[i+2].y + qB2.z*kr[i+2].z + qB2.w*kr[i+2].w;
      p13 += qB3.x*kr[i+3].x + qB3.y*kr[i+3].y + qB3.z*kr[i+3].z + qB3.w*kr[i+3].w;
    }
    float sA = ((p00 + p01) + (p02 + p03)) * 0.125f;
    float sB = ((p10 + p11) + (p12 + p13)) * 0.125f;
    sA = (lane < cnt) ? sA : -INFINITY;
    sB = (lane < cnt) ? sB : -INFINITY;
    float mA = sA, mB = sB;
    #pragma unroll
    for (int off = 32; off; off >>= 1) {
      mA = fmaxf(mA, __shfl_xor(mA, off));
      mB = fmaxf(mB, __shfl_xor(mB, off));
    }
    float eA = __expf(sA - mA);
    float eB = __expf(sB - mB);
    float sumA = eA, sumB = eB;
    #pragma unroll
    for (int off = 32; off; off >>= 1) {
      sumA += __shfl_xor(sumA, off);
      sumB += __shfl_xor(sumB, off);
    }
    lds_fence();
    sa[lane]      = eA;
    sa[64 + lane] = eB;
    lds_fence();
    float c00=0.f,c01=0.f,c02=0.f,c03=0.f;
    float c10=0.f,c11=0.f,c12=0.f,c13=0.f;
    #pragma unroll
    for (int i = 0; i < 16; i++) {
      float4 aA = sa4[i];
      float4 aB = sa4[16 + i];
      c00 += aA.x * vt[4*i + 0];
      c01 += aA.y * vt[4*i + 1];
      c02 += aA.z * vt[4*i + 2];
      c03 += aA.w * vt[4*i + 3];
      c10 += aB.x * vt[4*i + 0];
      c11 += aB.y * vt[4*i + 1];
      c12 += aB.z * vt[4*i + 2];
      c13 += aB.w * vt[4*i + 3];
    }
    {
      float ctxd = ((c00 + c01) + (c02 + c03)) / sumA;
      int qrow = __shfl(qidx_v, j0);
      ctx[((size_t)(b * Ll + qrow)) * 512 + h * 64 + lane] = ctxd;
    }
    if (j1v < qn) {
      float ctxd = ((c10 + c11) + (c12 + c13)) / sumB;
      int qrow = __shfl(qidx_v, j1v);
      ctx[((size_t)(b * Ll + qrow)) * 512 + h * 64 + lane] = ctxd;
    }
  }
}

// ---------------------------------------------------------------------------
// T[h,dk,n] = sum_r U[h,dk,r] * V[h,r,n]  (unchanged)
// ---------------------------------------------------------------------------
__global__ __launch_bounds__(256) void uv_kernel(
    const float* __restrict__ U, const float* __restrict__ V, float* __restrict__ T)
{
  int idx = blockIdx.x * 256 + threadIdx.x;
  int n = idx & 511, dk = (idx >> 9) & 63, h = idx >> 15;
  float acc = 0.f;
  #pragma unroll
  for (int r = 0; r < 32; r++)
    acc += U[((size_t)h * 64 + dk) * 32 + r] * V[((size_t)h * 32 + r) * 512 + n];
  T[idx] = acc;
}

// ---------------------------------------------------------------------------
// Mf[h*64+dk, n] = sum_c T[h,dk,c] * Wo[h*512+c, n].  (unchanged R15)
// ---------------------------------------------------------------------------
__global__ __launch_bounds__(64) void m_kernel(
    const float* __restrict__ T, const float* __restrict__ Wo, float* __restrict__ Mf)
{
  __shared__ float As[2][32 * 16];
  __shared__ float Bs[2][16 * 64];
  const int lane = threadIdx.x;
  const int h  = blockIdx.z;
  const int m0 = blockIdx.y * 32;
  const int n0 = blockIdx.x * 64;
  const int tx = lane & 15, ty = lane >> 4;

  const float* Tb = T + (size_t)h * 64 * 512;
  const float* Wb = Wo + (size_t)h * 512 * 512;

  const float* aSrc[2];
  #pragma unroll
  for (int j = 0; j < 2; j++) {
    int row  = 16*j + (lane >> 2);
    int key  = (row >> 3) & 3;
    int sK4  = (lane & 3) ^ key;
    aSrc[j] = Tb + (size_t)(m0 + row) * 512 + (sK4 << 2);
  }
  const float* bSrc[4];
  #pragma unroll
  for (int j = 0; j < 4; j++) {
    int krow = 4*j + (lane >> 4);
    bSrc[j] = Wb + (size_t)krow * 512 + n0 + ((lane & 15) << 2);
  }

  #pragma unroll
  for (int j = 0; j < 2; j++) gl_lds16(aSrc[j], &As[0][j*256]);
  #pragma unroll
  for (int j = 0; j < 4; j++) gl_lds16(bSrc[j], &Bs[0][j*256]);

  float acc[8][4] = {};
  for (int t = 0; t < 32; t++) {
    const int cur = t & 1;
    if (t < 31) {
      const int ks = (t + 1) * 16;
      const int nb = cur ^ 1;
      #pragma unroll
      for (int j = 0; j < 2; j++) gl_lds16(aSrc[j] + ks,              &As[nb][j*256]);
      #pragma unroll
      for (int j = 0; j < 4; j++) gl_lds16(bSrc[j] + (size_t)ks*512,  &Bs[nb][j*256]);
      VM_WAIT(6);
    } else {
      VM_WAIT(0);
    }

    const float* Ac = &As[cur][0];
    const float* Bc = &Bs[cur][0];
    #pragma unroll
    for (int kk4 = 0; kk4 < 4; kk4++) {
      float4 a[8];
      #pragma unroll
      for (int i = 0; i < 8; i++)
        a[i] = *(const float4*)&Ac[(ty*8 + i)*16 + ((kk4 ^ ty) << 2)];
      #pragma unroll
      for (int s = 0; s < 4; s++) {
        const int kk = kk4*4 + s;
        float4 b0 = *(const float4*)&Bc[kk*64 + tx*4];
        #pragma unroll
        for (int i = 0; i < 8; i++) {
          const float as = (s==0) ? a[i].x : (s==1) ? a[i].y
                         : (s==2) ? a[i].z : a[i].w;
          acc[i][0] += as * b0.x;  acc[i][1] += as * b0.y;
          acc[i][2] += as * b0.z;  acc[i][3] += as * b0.w;
        }
      }
    }
  }

  #pragma unroll
  for (int i = 0; i < 8; i++) {
    int row = h*64 + m0 + ty*8 + i;
    #pragma unroll
    for (int j = 0; j < 4; j++)
      Mf[(size_t)row * 512 + n0 + tx*4 + j] = acc[i][j];
  }
}

// ---------------------------------------------------------------------------
// OUT(4096x512) = CTX @ Mf + bo.  (unchanged R15)
// ---------------------------------------------------------------------------
__global__ __launch_bounds__(64) void out_gemm(
    const float* __restrict__ A, const float* __restrict__ Bm,
    const float* __restrict__ bias, float* __restrict__ C)
{
  __shared__ float As[2][32 * 16];
  __shared__ float Bs[2][16 * 64];
  const int lane = threadIdx.x;
  const int m0 = blockIdx.y * 32;
  const int n0 = blockIdx.x * 64;
  const int tx = lane & 15, ty = lane >> 4;

  const float* aSrc[2];
  #pragma unroll
  for (int j = 0; j < 2; j++) {
    int row  = 16*j + (lane >> 2);
    int key  = (row >> 3) & 3;
    int sK4  = (lane & 3) ^ key;
    aSrc[j] = A + (size_t)(m0 + row) * 512 + (sK4 << 2);
  }
  const float* bSrc[4];
  #pragma unroll
  for (int j = 0; j < 4; j++) {
    int krow = 4*j + (lane >> 4);
    bSrc[j] = Bm + (size_t)krow * 512 + n0 + ((lane & 15) << 2);
  }

  #pragma unroll
  for (int j = 0; j < 2; j++) gl_lds16(aSrc[j], &As[0][j*256]);
  #pragma unroll
  for (int j = 0; j < 4; j++) gl_lds16(bSrc[j], &Bs[0][j*256]);

  float acc[8][4] = {};
  for (int t = 0; t < 32; t++) {
    const int cur = t & 1;
    if (t < 31) {
      const int ks = (t + 1) * 16;
      const int nb = cur ^ 1;
      #pragma unroll
      for (int j = 0; j < 2; j++) gl_lds16(aSrc[j] + ks,              &As[nb][j*256]);
      #pragma unroll
      for (int j = 0; j < 4; j++) gl_lds16(bSrc[j] + (size_t)ks*512,  &Bs[nb][j*256]);
      VM_WAIT(6);
    } else {
      VM_WAIT(0);
    }

    const float* Ac = &As[cur][0];
    const float* Bc = &Bs[cur][0];
    #pragma unroll
    for (int kk4 = 0; kk4 < 4; kk4++) {
      float4 a[8];
      #pragma unroll
      for (int i = 0; i < 8; i++)
        a[i] = *(const float4*)&Ac[(ty*8 + i)*16 + ((kk4 ^ ty) << 2)];
      #pragma unroll
      for (int s = 0; s < 4; s++) {
        const int kk = kk4*4 + s;
        float4 b0 = *(const float4*)&Bc[kk*64 + tx*4];
        #pragma unroll
        for (int i = 0; i < 8; i++) {
          const float as = (s==0) ? a[i].x : (s==1) ? a[i].y
                         : (s==2) ? a[i].z : a[i].w;
          acc[i][0] += as * b0.x;  acc[i][1] += as * b0.y;
          acc[i][2] += as * b0.z;  acc[i][3] += as * b0.w;
        }
      }
    }
  }

  #pragma unroll
  for (int i = 0; i < 8; i++) {
    int m = m0 + ty*8 + i;
    #pragma unroll
    for (int j = 0; j < 4; j++) {
      int n = n0 + tx*4 + j;
      C[(size_t)m * 512 + n] = acc[i][j] + bias[n];
    }
  }
}

// ---------------------------------------------------------------------------
extern "C" void kernel_launch(void* const* d_in, const int* in_sizes, int n_in,
                              void* d_out, int out_size, void* d_ws, size_t ws_size,
                              hipStream_t stream)
{
  const float* query = (const float*)d_in[0];
  const float* key   = (const float*)d_in[1];
  const float* value = (const float*)d_in[2];
  const float* Wq = (const float*)d_in[3];
  const float* bq = (const float*)d_in[4];
  const float* Wk = (const float*)d_in[5];
  const float* bk = (const float*)d_in[6];
  const float* Wv = (const float*)d_in[7];
  const float* bv = (const float*)d_in[8];
  const float* U  = (const float*)d_in[9];
  const float* V  = (const float*)d_in[10];
  const float* rv = (const float*)d_in[11];
  const float* Wo = (const float*)d_in[12];
  const float* bo = (const float*)d_in[13];
  float* out = (float*)d_out;

  float* ws = (float*)d_ws;
  const size_t NQKV = (size_t)Bb * Hh * Ll * DKq;
  float* qb   = ws;
  float* kb   = qb + NQKV;
  float* vb   = kb + NQKV;
  float* ctx  = vb + NQKV;
  float* T    = ctx + NQKV;
  float* Mf   = T + (size_t)Hh * DKq * 512;
  int* qhash  = (int*)(Mf + 512 * 512);
  int* khash  = qhash + Bb * Hh * Ll;
  int* kcand  = khash + Bb * Hh * Ll;
  int* kcount = kcand + Bb * Hh * NBUCK * KMAX;   // unused (layout keep)
  int* qoff   = kcount + Bb * Hh * NBUCK;         // unused (layout keep)
  int* qlist  = qoff + Bb * Hh * (NBUCK + 1);
  int4* items = (int4*)(qlist + Bb * Hh * Ll);    // 16B-aligned offset
  int* nitems = (int*)(items + MAX_ITEMS);

  proj_kernel<<<dim3(8, 256, 3), 64, 0, stream>>>(query, key, value,
                                                  Wq, Wk, Wv, bq, bk, bv,
                                                  qb, kb, vb);
  hash_kernel<<<(2 * Bb * Hh * Ll * 64) / 256, 256, 0, stream>>>(qb, kb, rv, qhash, khash);
  hipMemsetAsync(nitems, 0, sizeof(int), stream);
  bucket_kernel<<<Bb * Hh, 256, 0, stream>>>(qhash, khash, qlist, kcand, items, nitems);
  attn_kernel<<<MAX_ITEMS / 4, 256, 0, stream>>>(qb, kb, vb, qlist, kcand,
                                                 items, nitems, ctx);
  uv_kernel<<<(Hh * DKq * 512) / 256, 256, 0, stream>>>(U, V, T);
  m_kernel<<<dim3(8, 2, 8), 64, 0, stream>>>(T, Wo, Mf);
  out_gemm<<<dim3(8, 128), 64, 0, stream>>>(ctx, Mf, bo, out);
}

// Round 21
// 251.860 us; speedup vs baseline: 1.0440x; 1.0430x over previous
//
#include <hip/hip_runtime.h>
#include <math.h>

// Problem constants (from reference)
#define Bb 2
#define Ll 2048
#define Dd 512
#define Hh 8
#define DKq 64
#define NBUCK 16
#define KMAX 64
#define MAX_ITEMS 2304   // chunk-16 bound: 16 bh * (128 + 16) = 2304

// ---------------------------------------------------------------------------
// Direct global->LDS DMA (gfx950), 16B per lane.  LDS dest = uniform base +
// lane*16 (linear); per-lane GLOBAL address carries any swizzle (m173/m201).
// ---------------------------------------------------------------------------
__device__ __forceinline__ void gl_lds16(const float* g, float* l) {
  __builtin_amdgcn_global_load_lds(
      (const __attribute__((address_space(1))) void*)g,
      (__attribute__((address_space(3))) void*)l, 16, 0, 0);
}

// Counted vmcnt wait, NO barrier (single-wave blocks are self-paced).
// vmcnt retires IN ORDER (round-11 lesson): with only staging DMAs on the
// counter, vmcnt(6) == "tile t's 6 loads done, t+1's 6 may fly".
#define VM_WAIT(N)                                                \
  do {                                                            \
    asm volatile("s_waitcnt vmcnt(" #N ")" ::: "memory");         \
    __builtin_amdgcn_sched_barrier(0);                            \
  } while (0)

// ---------------------------------------------------------------------------
// Projection GEMM (round-13 version -- best measured: ~95 us, VALUBusy ~57%).
// Single-wave blocks, BM=32 BN=64 BK=16, 8x4 microtile, grid (8,128,3) =
// 3072 blocks = 12 waves/CU.  DMA staging + counted vmcnt(6), no barrier.
// Per-output FMA chain is ascending-k -> bit-identical q/k (LSH-critical).
// (R17 A-from-global and R19/20 BM=16 variants both measured worse.)
// ---------------------------------------------------------------------------
__global__ __launch_bounds__(64) void proj_kernel(
    const float* __restrict__ Xq, const float* __restrict__ Xk, const float* __restrict__ Xv,
    const float* __restrict__ Wq, const float* __restrict__ Wk, const float* __restrict__ Wv,
    const float* __restrict__ bq, const float* __restrict__ bk, const float* __restrict__ bv,
    float* __restrict__ qb, float* __restrict__ kb, float* __restrict__ vb)
{
  const float *X, *W, *bias; float* dst;
  if (blockIdx.z == 0)      { X=Xq; W=Wq; bias=bq; dst=qb; }
  else if (blockIdx.z == 1) { X=Xk; W=Wk; bias=bk; dst=kb; }
  else                      { X=Xv; W=Wv; bias=bv; dst=vb; }
  __shared__ float As[2][32 * 16];
  __shared__ float Bs[2][16 * 64];
  const int lane = threadIdx.x;
  const int m0 = blockIdx.y * 32;
  const int n0 = blockIdx.x * 64;
  const int tx = lane & 15, ty = lane >> 4;

  const float* aSrc[2];
  #pragma unroll
  for (int j = 0; j < 2; j++) {
    int row  = 16*j + (lane >> 2);
    int key  = (row >> 3) & 3;
    int sK4  = (lane & 3) ^ key;
    aSrc[j] = X + (size_t)(m0 + row) * 512 + (sK4 << 2);
  }
  const float* bSrc[4];
  #pragma unroll
  for (int j = 0; j < 4; j++) {
    int krow = 4*j + (lane >> 4);
    bSrc[j] = W + (size_t)krow * 512 + n0 + ((lane & 15) << 2);
  }

  #pragma unroll
  for (int j = 0; j < 2; j++) gl_lds16(aSrc[j], &As[0][j*256]);
  #pragma unroll
  for (int j = 0; j < 4; j++) gl_lds16(bSrc[j], &Bs[0][j*256]);

  float acc[8][4] = {};
  for (int t = 0; t < 32; t++) {
    const int cur = t & 1;
    if (t < 31) {
      const int ks = (t + 1) * 16;
      const int nb = cur ^ 1;
      #pragma unroll
      for (int j = 0; j < 2; j++) gl_lds16(aSrc[j] + ks,              &As[nb][j*256]);
      #pragma unroll
      for (int j = 0; j < 4; j++) gl_lds16(bSrc[j] + (size_t)ks*512,  &Bs[nb][j*256]);
      VM_WAIT(6);
    } else {
      VM_WAIT(0);
    }

    const float* Ac = &As[cur][0];
    const float* Bc = &Bs[cur][0];
    #pragma unroll
    for (int kk4 = 0; kk4 < 4; kk4++) {
      float4 a[8];
      #pragma unroll
      for (int i = 0; i < 8; i++)
        a[i] = *(const float4*)&Ac[(ty*8 + i)*16 + ((kk4 ^ ty) << 2)];
      #pragma unroll
      for (int s = 0; s < 4; s++) {
        const int kk = kk4*4 + s;
        float4 b0 = *(const float4*)&Bc[kk*64 + tx*4];
        #pragma unroll
        for (int i = 0; i < 8; i++) {
          const float as = (s==0) ? a[i].x : (s==1) ? a[i].y
                         : (s==2) ? a[i].z : a[i].w;
          acc[i][0] += as * b0.x;  acc[i][1] += as * b0.y;
          acc[i][2] += as * b0.z;  acc[i][3] += as * b0.w;
        }
      }
    }
  }

  const int head = n0 >> 6;
  const int d0 = tx * 4;
  #pragma unroll
  for (int i = 0; i < 8; i++) {
    int m = m0 + ty*8 + i;
    int b = m >> 11, l = m & 2047;
    float* drow = &dst[(((size_t)b*Hh + head)*Ll + l)*DKq];
    #pragma unroll
    for (int j = 0; j < 4; j++) drow[d0 + j] = acc[i][j] + bias[n0 + tx*4 + j];
  }
}

// ---------------------------------------------------------------------------
// LSH hash (unchanged)
// ---------------------------------------------------------------------------
__global__ __launch_bounds__(256) void hash_kernel(
    const float* __restrict__ qb, const float* __restrict__ kb,
    const float* __restrict__ rv, int* __restrict__ qhash, int* __restrict__ khash)
{
  int gwave = (blockIdx.x * blockDim.x + threadIdx.x) >> 6;
  int lane = threadIdx.x & 63;
  const int NR = Bb * Hh * Ll;
  if (gwave >= 2 * NR) return;
  int isK = gwave >= NR;
  int row = isK ? gwave - NR : gwave;
  int h = (row >> 11) & 7;
  const float* src = isK ? kb : qb;
  float x = src[(size_t)row * DKq + lane];
  float r = rv[h * DKq + lane];
  float v = (x > 0.0f) ? r : 0.0f;
  #pragma unroll
  for (int off = 32; off; off >>= 1) v += __shfl_xor(v, off);
  if (lane == 0) {
    float fb = floorf(v * 0.125f);
    int ib = (int)fb;
    int bucket = ib & 15;
    (isK ? khash : qhash)[row] = bucket;
  }
}

// ---------------------------------------------------------------------------
// First <=64 ascending key indices per (b,h,bucket)
// ---------------------------------------------------------------------------
__global__ __launch_bounds__(64) void kcand_kernel(
    const int* __restrict__ khash, int* __restrict__ kcand, int* __restrict__ kcount)
{
  int bh = blockIdx.x >> 4;
  int bucket = blockIdx.x & 15;
  int lane = threadIdx.x;
  const int* kh = &khash[bh * Ll];
  int* cl = &kcand[(size_t)blockIdx.x * KMAX];
  int total = 0;
  for (int c0 = 0; c0 < Ll && total < KMAX; c0 += 64) {
    int hv = kh[c0 + lane];
    unsigned long long m = __ballot(hv == bucket);
    int pre = __popcll(m & ((1ULL << lane) - 1ULL));
    if (hv == bucket && total + pre < KMAX) cl[total + pre] = c0 + lane;
    total += __popcll(m);
  }
  if (lane == 0) kcount[blockIdx.x] = total < KMAX ? total : KMAX;
}

// ---------------------------------------------------------------------------
// Group queries by bucket per (b,h)
// ---------------------------------------------------------------------------
__global__ __launch_bounds__(256) void qlist_kernel(
    const int* __restrict__ qhash, int* __restrict__ qoff, int* __restrict__ qlist)
{
  int bh = blockIdx.x;
  __shared__ int cnt[NBUCK], cur[NBUCK], off[NBUCK + 1];
  if (threadIdx.x < NBUCK) cnt[threadIdx.x] = 0;
  __syncthreads();
  const int* qh = &qhash[bh * Ll];
  for (int l = threadIdx.x; l < Ll; l += 256) atomicAdd(&cnt[qh[l]], 1);
  __syncthreads();
  if (threadIdx.x == 0) {
    int s = 0;
    for (int i = 0; i < NBUCK; i++) { off[i] = s; cur[i] = s; s += cnt[i]; }
    off[NBUCK] = s;
  }
  __syncthreads();
  if (threadIdx.x < NBUCK + 1) qoff[bh * (NBUCK + 1) + threadIdx.x] = off[threadIdx.x];
  for (int l = threadIdx.x; l < Ll; l += 256) {
    int p = atomicAdd(&cur[qh[l]], 1);
    qlist[bh * Ll + p] = l;
  }
}

// ---------------------------------------------------------------------------
// Deterministic worklist: one item per active (bh,bucket,chunk-of-16-queries).
// ---------------------------------------------------------------------------
__global__ __launch_bounds__(256) void worklist_kernel(
    const int* __restrict__ qoff, const int* __restrict__ kcount,
    int4* __restrict__ items, int* __restrict__ nitems)
{
  int t = threadIdx.x;
  int bh = t >> 4, bucket = t & 15;
  int o0 = qoff[bh * 17 + bucket], o1 = qoff[bh * 17 + bucket + 1];
  int cnt = kcount[t];
  int nq = o1 - o0;
  int n = (cnt > 0) ? ((nq + 15) >> 4) : 0;
  __shared__ int sc[256];
  sc[t] = n;
  __syncthreads();
  for (int off = 1; off < 256; off <<= 1) {
    int v = (t >= off) ? sc[t - off] : 0;
    __syncthreads();
    sc[t] += v;
    __syncthreads();
  }
  int start = sc[t] - n;
  for (int i = 0; i < n; i++) {
    int q0 = 16 * i;
    int qn = nq - q0; if (qn > 16) qn = 16;
    items[start + i] = make_int4(t, o0 + q0, qn, cnt);
  }
  if (t == 255) nitems[0] = sc[255];
}

// ---------------------------------------------------------------------------
// LDS fence for same-wave cross-lane LDS dependences (rule #18).
// ---------------------------------------------------------------------------
__device__ __forceinline__ void lds_fence() {
  asm volatile("s_waitcnt lgkmcnt(0)" ::: "memory");
  __builtin_amdgcn_sched_barrier(0);
}

// ---------------------------------------------------------------------------
// Attention (round-16 version): one WAVE per item (<=16 q x <=64 cand x
// 64 dim), paired query processing -- dual QK dots / dual shfl reduces /
// one sa[128] write + one fence pair / dual PV chains per 2 queries.
// K rows in regs (lane=c), V^T in regs (lane=d), Q via wave-private LDS.
// ---------------------------------------------------------------------------
__global__ __launch_bounds__(256, 2) void attn_kernel(
    const float* __restrict__ qb, const float* __restrict__ kb, const float* __restrict__ vb,
    const int* __restrict__ qlist, const int* __restrict__ kcand,
    const int4* __restrict__ items, const int* __restrict__ nitems,
    float* __restrict__ ctx)
{
  __shared__ float qs_all[4][16 * 64];
  __shared__ float sa_all[4][128];
  const int wid = threadIdx.x >> 6, lane = threadIdx.x & 63;
  const int idx = blockIdx.x * 4 + wid;
  if (idx >= nitems[0]) return;          // wave-uniform exit
  const int4 it = items[idx];
  const int code = it.x, qstart = it.y, qn = it.z, cnt = it.w;
  const int bh = code >> 4;
  float* qs = qs_all[wid];
  float* sa = sa_all[wid];

  const float* qbh = qb + (size_t)bh * Ll * DKq;
  const float* kbh = kb + (size_t)bh * Ll * DKq;
  const float* vbh = vb + (size_t)bh * Ll * DKq;

  int qidx_v = (lane < qn)  ? qlist[bh * Ll + qstart + lane] : 0;
  int cidx_v = (lane < cnt) ? kcand[(size_t)code * KMAX + lane] : 0;

  float4 kr[16];
  {
    const float4* krow = (const float4*)kbh + (size_t)cidx_v * 16;
    #pragma unroll
    for (int i = 0; i < 16; i++) kr[i] = krow[i];
  }
  float vt[64];
  #pragma unroll
  for (int c = 0; c < 64; c++) {
    int rowc = __shfl(cidx_v, c);
    vt[c] = vbh[(size_t)rowc * DKq + lane];
  }
  #pragma unroll
  for (int i = 0; i < 4; i++) {
    int f = lane + 64 * i;
    int r = f >> 4, c4 = f & 15;
    int qrow = __shfl(qidx_v, r);
    float4 qv = *((const float4*)qbh + (size_t)qrow * 16 + c4);
    *(float4*)&qs[r * 64 + c4 * 4] = qv;
  }
  lds_fence();

  const int b = bh >> 3, h = bh & 7;
  const float4* qs4 = (const float4*)qs;
  const float4* sa4 = (const float4*)sa;

  for (int jj = 0; jj < qn; jj += 2) {
    const int j0  = jj;
    const int j1v = jj + 1;
    const int j1r = (j1v < qn) ? j1v : j0;
    float p00=0.f,p01=0.f,p02=0.f,p03=0.f;
    float p10=0.f,p11=0.f,p12=0.f,p13=0.f;
    #pragma unroll
    for (int i = 0; i < 16; i += 4) {
      float4 qA0 = qs4[j0*16 + i + 0];
      float4 qA1 = qs4[j0*16 + i + 1];
      float4 qA2 = qs4[j0*16 + i + 2];
      float4 qA3 = qs4[j0*16 + i + 3];
      float4 qB0 = qs4[j1r*16 + i + 0];
      float4 qB1 = qs4[j1r*16 + i + 1];
      float4 qB2 = qs4[j1r*16 + i + 2];
      float4 qB3 = qs4[j1r*16 + i + 3];
      p00 += qA0.x*kr[i+0].x + qA0.y*kr[i+0].y + qA0.z*kr[i+0].z + qA0.w*kr[i+0].w;
      p01 += qA1.x*kr[i+1].x + qA1.y*kr[i+1].y + qA1.z*kr[i+1].z + qA1.w*kr[i+1].w;
      p02 += qA2.x*kr[i+2].x + qA2.y*kr[i+2].y + qA2.z*kr[i+2].z + qA2.w*kr[i+2].w;
      p03 += qA3.x*kr[i+3].x + qA3.y*kr[i+3].y + qA3.z*kr[i+3].z + qA3.w*kr[i+3].w;
      p10 += qB0.x*kr[i+0].x + qB0.y*kr[i+0].y + qB0.z*kr[i+0].z + qB0.w*kr[i+0].w;
      p11 += qB1.x*kr[i+1].x + qB1.y*kr[i+1].y + qB1.z*kr[i+1].z + qB1.w*kr[i+1].w;
      p12 += qB2.x*kr[i+2].x + qB2.y*kr[i+2].y + qB2.z*kr[i+2].z + qB2.w*kr[i+2].w;
      p13 += qB3.x*kr[i+3].x + qB3.y*kr[i+3].y + qB3.z*kr[i+3].z + qB3.w*kr[i+3].w;
    }
    float sA = ((p00 + p01) + (p02 + p03)) * 0.125f;
    float sB = ((p10 + p11) + (p12 + p13)) * 0.125f;
    sA = (lane < cnt) ? sA : -INFINITY;
    sB = (lane < cnt) ? sB : -INFINITY;
    float mA = sA, mB = sB;
    #pragma unroll
    for (int off = 32; off; off >>= 1) {
      mA = fmaxf(mA, __shfl_xor(mA, off));
      mB = fmaxf(mB, __shfl_xor(mB, off));
    }
    float eA = __expf(sA - mA);
    float eB = __expf(sB - mB);
    float sumA = eA, sumB = eB;
    #pragma unroll
    for (int off = 32; off; off >>= 1) {
      sumA += __shfl_xor(sumA, off);
      sumB += __shfl_xor(sumB, off);
    }
    lds_fence();
    sa[lane]      = eA;
    sa[64 + lane] = eB;
    lds_fence();
    float c00=0.f,c01=0.f,c02=0.f,c03=0.f;
    float c10=0.f,c11=0.f,c12=0.f,c13=0.f;
    #pragma unroll
    for (int i = 0; i < 16; i++) {
      float4 aA = sa4[i];
      float4 aB = sa4[16 + i];
      c00 += aA.x * vt[4*i + 0];
      c01 += aA.y * vt[4*i + 1];
      c02 += aA.z * vt[4*i + 2];
      c03 += aA.w * vt[4*i + 3];
      c10 += aB.x * vt[4*i + 0];
      c11 += aB.y * vt[4*i + 1];
      c12 += aB.z * vt[4*i + 2];
      c13 += aB.w * vt[4*i + 3];
    }
    {
      float ctxd = ((c00 + c01) + (c02 + c03)) / sumA;
      int qrow = __shfl(qidx_v, j0);
      ctx[((size_t)(b * Ll + qrow)) * 512 + h * 64 + lane] = ctxd;
    }
    if (j1v < qn) {
      float ctxd = ((c10 + c11) + (c12 + c13)) / sumB;
      int qrow = __shfl(qidx_v, j1v);
      ctx[((size_t)(b * Ll + qrow)) * 512 + h * 64 + lane] = ctxd;
    }
  }
}

// ---------------------------------------------------------------------------
// T[h,dk,n] = sum_r U[h,dk,r] * V[h,r,n]
// ---------------------------------------------------------------------------
__global__ __launch_bounds__(256) void uv_kernel(
    const float* __restrict__ U, const float* __restrict__ V, float* __restrict__ T)
{
  int idx = blockIdx.x * 256 + threadIdx.x;
  int n = idx & 511, dk = (idx >> 9) & 63, h = idx >> 15;
  float acc = 0.f;
  #pragma unroll
  for (int r = 0; r < 32; r++)
    acc += U[((size_t)h * 64 + dk) * 32 + r] * V[((size_t)h * 32 + r) * 512 + n];
  T[idx] = acc;
}

// ---------------------------------------------------------------------------
// Mf[h*64+dk, n] = sum_c T[h,dk,c] * Wo[h*512+c, n].  (R15 single-wave)
// ---------------------------------------------------------------------------
__global__ __launch_bounds__(64) void m_kernel(
    const float* __restrict__ T, const float* __restrict__ Wo, float* __restrict__ Mf)
{
  __shared__ float As[2][32 * 16];
  __shared__ float Bs[2][16 * 64];
  const int lane = threadIdx.x;
  const int h  = blockIdx.z;
  const int m0 = blockIdx.y * 32;
  const int n0 = blockIdx.x * 64;
  const int tx = lane & 15, ty = lane >> 4;

  const float* Tb = T + (size_t)h * 64 * 512;
  const float* Wb = Wo + (size_t)h * 512 * 512;

  const float* aSrc[2];
  #pragma unroll
  for (int j = 0; j < 2; j++) {
    int row  = 16*j + (lane >> 2);
    int key  = (row >> 3) & 3;
    int sK4  = (lane & 3) ^ key;
    aSrc[j] = Tb + (size_t)(m0 + row) * 512 + (sK4 << 2);
  }
  const float* bSrc[4];
  #pragma unroll
  for (int j = 0; j < 4; j++) {
    int krow = 4*j + (lane >> 4);
    bSrc[j] = Wb + (size_t)krow * 512 + n0 + ((lane & 15) << 2);
  }

  #pragma unroll
  for (int j = 0; j < 2; j++) gl_lds16(aSrc[j], &As[0][j*256]);
  #pragma unroll
  for (int j = 0; j < 4; j++) gl_lds16(bSrc[j], &Bs[0][j*256]);

  float acc[8][4] = {};
  for (int t = 0; t < 32; t++) {
    const int cur = t & 1;
    if (t < 31) {
      const int ks = (t + 1) * 16;
      const int nb = cur ^ 1;
      #pragma unroll
      for (int j = 0; j < 2; j++) gl_lds16(aSrc[j] + ks,              &As[nb][j*256]);
      #pragma unroll
      for (int j = 0; j < 4; j++) gl_lds16(bSrc[j] + (size_t)ks*512,  &Bs[nb][j*256]);
      VM_WAIT(6);
    } else {
      VM_WAIT(0);
    }

    const float* Ac = &As[cur][0];
    const float* Bc = &Bs[cur][0];
    #pragma unroll
    for (int kk4 = 0; kk4 < 4; kk4++) {
      float4 a[8];
      #pragma unroll
      for (int i = 0; i < 8; i++)
        a[i] = *(const float4*)&Ac[(ty*8 + i)*16 + ((kk4 ^ ty) << 2)];
      #pragma unroll
      for (int s = 0; s < 4; s++) {
        const int kk = kk4*4 + s;
        float4 b0 = *(const float4*)&Bc[kk*64 + tx*4];
        #pragma unroll
        for (int i = 0; i < 8; i++) {
          const float as = (s==0) ? a[i].x : (s==1) ? a[i].y
                         : (s==2) ? a[i].z : a[i].w;
          acc[i][0] += as * b0.x;  acc[i][1] += as * b0.y;
          acc[i][2] += as * b0.z;  acc[i][3] += as * b0.w;
        }
      }
    }
  }

  #pragma unroll
  for (int i = 0; i < 8; i++) {
    int row = h*64 + m0 + ty*8 + i;
    #pragma unroll
    for (int j = 0; j < 4; j++)
      Mf[(size_t)row * 512 + n0 + tx*4 + j] = acc[i][j];
  }
}

// ---------------------------------------------------------------------------
// OUT(4096x512) = CTX @ Mf + bo.  (R15 single-wave)
// ---------------------------------------------------------------------------
__global__ __launch_bounds__(64) void out_gemm(
    const float* __restrict__ A, const float* __restrict__ Bm,
    const float* __restrict__ bias, float* __restrict__ C)
{
  __shared__ float As[2][32 * 16];
  __shared__ float Bs[2][16 * 64];
  const int lane = threadIdx.x;
  const int m0 = blockIdx.y * 32;
  const int n0 = blockIdx.x * 64;
  const int tx = lane & 15, ty = lane >> 4;

  const float* aSrc[2];
  #pragma unroll
  for (int j = 0; j < 2; j++) {
    int row  = 16*j + (lane >> 2);
    int key  = (row >> 3) & 3;
    int sK4  = (lane & 3) ^ key;
    aSrc[j] = A + (size_t)(m0 + row) * 512 + (sK4 << 2);
  }
  const float* bSrc[4];
  #pragma unroll
  for (int j = 0; j < 4; j++) {
    int krow = 4*j + (lane >> 4);
    bSrc[j] = Bm + (size_t)krow * 512 + n0 + ((lane & 15) << 2);
  }

  #pragma unroll
  for (int j = 0; j < 2; j++) gl_lds16(aSrc[j], &As[0][j*256]);
  #pragma unroll
  for (int j = 0; j < 4; j++) gl_lds16(bSrc[j], &Bs[0][j*256]);

  float acc[8][4] = {};
  for (int t = 0; t < 32; t++) {
    const int cur = t & 1;
    if (t < 31) {
      const int ks = (t + 1) * 16;
      const int nb = cur ^ 1;
      #pragma unroll
      for (int j = 0; j < 2; j++) gl_lds16(aSrc[j] + ks,              &As[nb][j*256]);
      #pragma unroll
      for (int j = 0; j < 4; j++) gl_lds16(bSrc[j] + (size_t)ks*512,  &Bs[nb][j*256]);
      VM_WAIT(6);
    } else {
      VM_WAIT(0);
    }

    const float* Ac = &As[cur][0];
    const float* Bc = &Bs[cur][0];
    #pragma unroll
    for (int kk4 = 0; kk4 < 4; kk4++) {
      float4 a[8];
      #pragma unroll
      for (int i = 0; i < 8; i++)
        a[i] = *(const float4*)&Ac[(ty*8 + i)*16 + ((kk4 ^ ty) << 2)];
      #pragma unroll
      for (int s = 0; s < 4; s++) {
        const int kk = kk4*4 + s;
        float4 b0 = *(const float4*)&Bc[kk*64 + tx*4];
        #pragma unroll
        for (int i = 0; i < 8; i++) {
          const float as = (s==0) ? a[i].x : (s==1) ? a[i].y
                         : (s==2) ? a[i].z : a[i].w;
          acc[i][0] += as * b0.x;  acc[i][1] += as * b0.y;
          acc[i][2] += as * b0.z;  acc[i][3] += as * b0.w;
        }
      }
    }
  }

  #pragma unroll
  for (int i = 0; i < 8; i++) {
    int m = m0 + ty*8 + i;
    #pragma unroll
    for (int j = 0; j < 4; j++) {
      int n = n0 + tx*4 + j;
      C[(size_t)m * 512 + n] = acc[i][j] + bias[n];
    }
  }
}

// ---------------------------------------------------------------------------
extern "C" void kernel_launch(void* const* d_in, const int* in_sizes, int n_in,
                              void* d_out, int out_size, void* d_ws, size_t ws_size,
                              hipStream_t stream)
{
  const float* query = (const float*)d_in[0];
  const float* key   = (const float*)d_in[1];
  const float* value = (const float*)d_in[2];
  const float* Wq = (const float*)d_in[3];
  const float* bq = (const float*)d_in[4];
  const float* Wk = (const float*)d_in[5];
  const float* bk = (const float*)d_in[6];
  const float* Wv = (const float*)d_in[7];
  const float* bv = (const float*)d_in[8];
  const float* U  = (const float*)d_in[9];
  const float* V  = (const float*)d_in[10];
  const float* rv = (const float*)d_in[11];
  const float* Wo = (const float*)d_in[12];
  const float* bo = (const float*)d_in[13];
  float* out = (float*)d_out;

  float* ws = (float*)d_ws;
  const size_t NQKV = (size_t)Bb * Hh * Ll * DKq;
  float* qb   = ws;
  float* kb   = qb + NQKV;
  float* vb   = kb + NQKV;
  float* ctx  = vb + NQKV;
  float* T    = ctx + NQKV;
  float* Mf   = T + (size_t)Hh * DKq * 512;
  int* qhash  = (int*)(Mf + 512 * 512);
  int* khash  = qhash + Bb * Hh * Ll;
  int* kcand  = khash + Bb * Hh * Ll;
  int* kcount = kcand + Bb * Hh * NBUCK * KMAX;
  int* qoff   = kcount + Bb * Hh * NBUCK;
  int* qlist  = qoff + Bb * Hh * (NBUCK + 1);
  int4* items = (int4*)(qlist + Bb * Hh * Ll);    // 16B-aligned offset
  int* nitems = (int*)(items + MAX_ITEMS);

  proj_kernel<<<dim3(8, 128, 3), 64, 0, stream>>>(query, key, value,
                                                  Wq, Wk, Wv, bq, bk, bv,
                                                  qb, kb, vb);
  hash_kernel<<<(2 * Bb * Hh * Ll * 64) / 256, 256, 0, stream>>>(qb, kb, rv, qhash, khash);
  kcand_kernel<<<Bb * Hh * NBUCK, 64, 0, stream>>>(khash, kcand, kcount);
  qlist_kernel<<<Bb * Hh, 256, 0, stream>>>(qhash, qoff, qlist);
  worklist_kernel<<<1, 256, 0, stream>>>(qoff, kcount, items, nitems);
  attn_kernel<<<MAX_ITEMS / 4, 256, 0, stream>>>(qb, kb, vb, qlist, kcand,
                                                 items, nitems, ctx);
  uv_kernel<<<(Hh * DKq * 512) / 256, 256, 0, stream>>>(U, V, T);
  m_kernel<<<dim3(8, 2, 8), 64, 0, stream>>>(T, Wo, Mf);
  out_gemm<<<dim3(8, 128), 64, 0, stream>>>(ctx, Mf, bo, out);
}